// Round 6
// baseline (242.904 us; speedup 1.0000x reference)
//
#include <hip/hip_runtime.h>
#include <cstdint>

#define GC 32768
#define GN (2*GC)
#define GE (3*GC-2)

typedef _Float16 f16x8 __attribute__((ext_vector_type(8)));
typedef float f32x4 __attribute__((ext_vector_type(4)));

// ---- weight mapping (feature-space indices, i.e. K/2) ----
// G1 feature space: [h0c(F) h1c(F) h0p(F) h1p(F) e1(4) e2(4) e3(4)]
// G1 N space: [A(H) B(H) V(H)]  A=row0-horiz, B=row1-horiz, V=vertical
__device__ __forceinline__ float g1w(const float* w1, int F, int H, int f, int n) {
    if (n >= 3 * H) return 0.f;
    int t = n / H, h = n % H;
    const float* w = w1 + h * (2 * F + 4);
    if (t == 0) {
        if (f < F) return w[f];                                    // dst = h0c
        if (f >= 2*F && f < 3*F) return w[F + f - 2*F];            // src = h0p
        if (f >= 4*F && f < 4*F + 4) return w[2*F + f - 4*F];      // e1
    } else if (t == 1) {
        if (f >= F && f < 2*F) return w[f - F];                    // dst = h1c
        if (f >= 3*F && f < 4*F) return w[F + f - 3*F];            // src = h1p
        if (f >= 4*F + 4 && f < 4*F + 8) return w[2*F + f - (4*F+4)];   // e2
    } else {
        if (f < F) return w[F + f];                                // src = h0c
        if (f >= F && f < 2*F) return w[f - F];                    // dst = h1c
        if (f >= 4*F + 8 && f < 4*F + 12) return w[2*F + f - (4*F+8)];  // e3
    }
    return 0.f;
}
// G2: K-feature space = z [A(H) B(H) V(H)], N = [A(O) B(O) V(O)], block-diagonal
__device__ __forceinline__ float g2w(const float* wb, int H, int O, int f, int n) {
    if (f >= 3 * H || n >= 3 * O) return 0.f;
    if (f / H != n / O) return 0.f;
    return wb[(n % O) * H + (f % H)];
}

__device__ __forceinline__ uint32_t pkf16(float a, float b) {
    unsigned short ua = __builtin_bit_cast(unsigned short, (_Float16)a);
    unsigned short ub = __builtin_bit_cast(unsigned short, (_Float16)b);
    return (uint32_t)ua | ((uint32_t)ub << 16);
}
// split v into f16 hi/lo pair packed in one dword (hi at even K-slot = low half)
__device__ __forceinline__ uint32_t splitpk(float v) {
    _Float16 h = (_Float16)v;
    _Float16 lo = (_Float16)(v - (float)h);
    return (uint32_t)__builtin_bit_cast(unsigned short, h) |
           ((uint32_t)__builtin_bit_cast(unsigned short, lo) << 16);
}

// 29 B-fragments; K-slot pair (2f,2f+1) both carry w(f)
// 0,1: L1G1 c0,c1 | 2: L1G2 | 3-6: L2G1 (nt*2+c) | 7-10: L2G2 | 11-19: L3G1 (nt*3+c) | 20-28: L3G2
__global__ void build_frags(const float* __restrict__ w1a, const float* __restrict__ w1b,
                            const float* __restrict__ w2a, const float* __restrict__ w2b,
                            const float* __restrict__ w3a, const float* __restrict__ w3b,
                            uint4* __restrict__ tab) {
    int tid = blockIdx.x * 256 + threadIdx.x;
    if (tid >= 29 * 64) return;
    int fr = tid >> 6, l = tid & 63;
    int col = l & 15, kq = l >> 4;
    float v[8];
#pragma unroll
    for (int i = 0; i < 8; ++i) {
        int kin = kq * 8 + i;
        float val;
        if (fr < 2)        val = g1w(w1a, 2, 4, (fr * 32 + kin) >> 1, col);
        else if (fr == 2)  val = g2w(w1b, 4, 4, kin >> 1, col);
        else if (fr < 7)  { int nt = (fr - 3) >> 1, c = (fr - 3) & 1;
                            val = g1w(w2a, 4, 8, (c * 32 + kin) >> 1, nt * 16 + col); }
        else if (fr < 11) { int nt = (fr - 7) >> 1, c = (fr - 7) & 1;
                            val = g2w(w2b, 8, 8, (c * 32 + kin) >> 1, nt * 16 + col); }
        else if (fr < 20) { int nt = (fr - 11) / 3, c = (fr - 11) % 3;
                            val = g1w(w3a, 8, 16, (c * 32 + kin) >> 1, nt * 16 + col); }
        else              { int nt = (fr - 20) / 3, c = (fr - 20) % 3;
                            val = g2w(w3b, 16, 16, (c * 32 + kin) >> 1, nt * 16 + col); }
        v[i] = val;
    }
    uint4 o;
    o.x = pkf16(v[0], v[1]); o.y = pkf16(v[2], v[3]);
    o.z = pkf16(v[4], v[5]); o.w = pkf16(v[6], v[7]);
    tab[fr * 64 + l] = o;
}

// LDS per batch-row (u32 per feature = f16 hi/lo pair):
// E:   0..47   e1(16B) e2(16B) e3(16B)
// X:  48..79   cur[x0c x1c](16B) prev[x0p x1p](16B)
// H2: 80..143  2 parity slots x [h0(4)|h1(4)] = 32B
// H3: 144..271 2 parity slots x [h0(8)|h1(8)] = 64B
// Z: 272..463  48 u32
#define OFF_E  0
#define OFF_X  48
#define OFF_H2 80
#define OFF_H3 144
#define OFF_Z  272
#define ROWB   464

__device__ __forceinline__ f32x4 mfma16(uint4 a, uint4 b, f32x4 c) {
    return __builtin_amdgcn_mfma_f32_16x16x32_f16(
        __builtin_bit_cast(f16x8, a), __builtin_bit_cast(f16x8, b), c, 0, 0, 0);
}

__global__ __launch_bounds__(256, 2) void gnn_mfma(
    const float* __restrict__ x, const float* __restrict__ e,
    const float* __restrict__ b1a, const float* __restrict__ b1b,
    const float* __restrict__ b2a, const float* __restrict__ b2b,
    const float* __restrict__ b3a, const float* __restrict__ b3b,
    const float* __restrict__ wmu, const float* __restrict__ bmu,
    const uint4* __restrict__ tab, float* __restrict__ out)
{
    __shared__ __align__(16) char smem[4 * 16 * ROWB];
    const int l  = threadIdx.x & 63;
    const int wv = threadIdx.x >> 6;
    char* wbase = smem + wv * 16 * ROWB;

    const int gw    = blockIdx.x * 4 + wv;
    const int bg    = gw & 3;           // batch group of 16
    const int strip = gw >> 2;          // 1024 strips x 32 cols
    const int j0    = strip * 32;

    const int n = l & 15;
    const int q = l >> 4;

    // zero wave-private slice (16 rows x 464B = 1856 dwords)
    {
        uint32_t* p = (uint32_t*)wbase;
#pragma unroll
        for (int i = 0; i < 29; ++i) p[l * 29 + i] = 0u;
    }

    uint4 BF[29];
#pragma unroll
    for (int f = 0; f < 29; ++f) BF[f] = tab[f * 64 + l];

    const float zb1 = b1a[n & 3], zb2 = b2a[n & 7], zb3 = b3a[n];
    const float cb1 = b1b[n & 3], cb2 = b2b[n & 7], cb3 = b3b[n];
    const float wm0 = wmu[n], wm1 = wmu[16 + n];
    const float bm  = bmu[0];

    const int mB = bg * 16 + n;
    const size_t xrow = (size_t)mB * GN * 2;
    const size_t erow = (size_t)mB * GE * 4;

    char* rr = wbase + n * ROWB;          // A-fragment reads: row = batch n
    char* wr = wbase + (q * 4) * ROWB;    // D writes: row = q*4 + r
    char* lr = wbase + n * ROWB;          // staging writes: row = batch n

    const f32x4 zero = {0.f, 0.f, 0.f, 0.f};

    float4 ldA, ldB;
    auto issue = [&](int jn) {
        if (q == 0)      { int i2 = min(max(jn - 1, 0), GC - 2);
                           ldA = *(const float4*)(e + erow + 4 * (size_t)i2); }
        else if (q == 1) { int i2 = min(max(jn - 1, 0), GC - 2);
                           ldA = *(const float4*)(e + erow + 4 * (size_t)(GC - 1 + i2)); }
        else if (q == 2) { int i2 = min(max(jn, 0), GC - 1);
                           ldA = *(const float4*)(e + erow + 4 * (size_t)(2 * (GC - 1) + i2)); }
        else {
            int jc = min(max(jn, 0), GC - 1), jp = min(max(jn - 1, 0), GC - 1);
            float2 a = *(const float2*)(x + xrow + 2 * (size_t)jc);
            float2 b = *(const float2*)(x + xrow + 2 * (size_t)(GC + jc));
            float2 c = *(const float2*)(x + xrow + 2 * (size_t)jp);
            float2 d = *(const float2*)(x + xrow + 2 * (size_t)(GC + jp));
            ldA = make_float4(a.x, a.y, b.x, b.y);
            ldB = make_float4(c.x, c.y, d.x, d.y);
        }
    };
    auto commit = [&]() {
        uint4 o;
        o.x = splitpk(ldA.x); o.y = splitpk(ldA.y);
        o.z = splitpk(ldA.z); o.w = splitpk(ldA.w);
        if (q < 3) { *(uint4*)(lr + OFF_E + q * 16) = o; }
        else {
            *(uint4*)(lr + OFF_X) = o;
            uint4 o2;
            o2.x = splitpk(ldB.x); o2.y = splitpk(ldB.y);
            o2.z = splitpk(ldB.z); o2.w = splitpk(ldB.w);
            *(uint4*)(lr + OFF_X + 16) = o2;
        }
    };

    issue(j0 - 2);
    commit();

    for (int it = 0; it <= 33; ++it) {
        const int j = j0 + it - 2;
        const int p = it & 1;
        const bool jpos = (j >= 1);

        if (it < 33) issue(j + 1);

        // ---------- layer 1 ----------
        {
            uint4 a0 = *(const uint4*)(rr + (q == 0 ? OFF_X : q == 1 ? OFF_X + 16
                                          : q == 2 ? OFF_E : OFF_E + 16));
            uint4 a1 = *(const uint4*)(rr + (q == 0 ? OFF_E + 32 : OFF_E));
            f32x4 d = mfma16(a0, BF[0], zero);
            d = mfma16(a1, BF[1], d);
#pragma unroll
            for (int r = 0; r < 4; ++r)
                *(uint32_t*)(wr + OFF_Z + n * 4 + r * ROWB) = splitpk(fmaxf(d[r] + zb1, 0.f));

            uint4 az = *(const uint4*)(rr + OFF_Z + q * 16);
            f32x4 d2 = mfma16(az, BF[2], zero);
            float sB[4], sV[4];
#pragma unroll
            for (int r = 0; r < 4; ++r) {
                sB[r] = __shfl(d2[r], l + 4);
                sV[r] = __shfl(d2[r], l + 8);
            }
            if (n < 4) {
#pragma unroll
                for (int r = 0; r < 4; ++r) {
                    float h0 = jpos ? d2[r] + cb1 : 0.f;
                    float h1 = (jpos ? fmaxf(sB[r], sV[r]) : sV[r]) + cb1;
                    *(uint32_t*)(wr + OFF_H2 + p * 32 + n * 4 + r * ROWB)      = splitpk(h0);
                    *(uint32_t*)(wr + OFF_H2 + p * 32 + 16 + n * 4 + r * ROWB) = splitpk(h1);
                }
            }
        }

        // ---------- layer 2 ----------
        {
            uint4 b0 = *(const uint4*)(rr + OFF_H2 + ((q < 2) ? p : (p ^ 1)) * 32 + (q & 1) * 16);
            uint4 b1 = *(const uint4*)(rr + (q == 0 ? OFF_E : q == 1 ? OFF_E + 16
                                           : q == 2 ? OFF_E + 32 : OFF_E));
            f32x4 t0 = mfma16(b0, BF[3], zero); t0 = mfma16(b1, BF[4], t0);
            f32x4 t1 = mfma16(b0, BF[5], zero); t1 = mfma16(b1, BF[6], t1);
#pragma unroll
            for (int r = 0; r < 4; ++r) {
                *(uint32_t*)(wr + OFF_Z + n * 4 + r * ROWB)      = splitpk(fmaxf(t0[r] + zb2, 0.f));
                *(uint32_t*)(wr + OFF_Z + 64 + n * 4 + r * ROWB) = splitpk(fmaxf(t1[r] + zb2, 0.f));
            }
            uint4 az0 = *(const uint4*)(rr + OFF_Z + q * 16);
            uint4 az1 = *(const uint4*)(rr + OFF_Z + 64 + q * 16);
            f32x4 u0 = mfma16(az0, BF[7], zero); u0 = mfma16(az1, BF[8], u0);
            f32x4 u1 = mfma16(az0, BF[9], zero); u1 = mfma16(az1, BF[10], u1);
            float sB2[4];
#pragma unroll
            for (int r = 0; r < 4; ++r) sB2[r] = __shfl(u0[r], l + 8);
            if (n < 8) {
#pragma unroll
                for (int r = 0; r < 4; ++r) {
                    float h0 = jpos ? u0[r] + cb2 : 0.f;
                    float h1 = (jpos ? fmaxf(sB2[r], u1[r]) : u1[r]) + cb2;
                    *(uint32_t*)(wr + OFF_H3 + p * 64 + n * 4 + r * ROWB)      = splitpk(h0);
                    *(uint32_t*)(wr + OFF_H3 + p * 64 + 32 + n * 4 + r * ROWB) = splitpk(h1);
                }
            }
        }

        // ---------- layer 3 + mu ----------
        if (it >= 2) {
            uint4 c0 = *(const uint4*)(rr + OFF_H3 + p * 64 + q * 16);
            uint4 c1 = *(const uint4*)(rr + OFF_H3 + (p ^ 1) * 64 + q * 16);
            uint4 c2 = *(const uint4*)(rr + (q == 0 ? OFF_E : q == 1 ? OFF_E + 16
                                           : q == 2 ? OFF_E + 32 : OFF_E));
            f32x4 w0 = mfma16(c0, BF[11], zero); w0 = mfma16(c1, BF[12], w0); w0 = mfma16(c2, BF[13], w0);
            f32x4 w1 = mfma16(c0, BF[14], zero); w1 = mfma16(c1, BF[15], w1); w1 = mfma16(c2, BF[16], w1);
            f32x4 w2 = mfma16(c0, BF[17], zero); w2 = mfma16(c1, BF[18], w2); w2 = mfma16(c2, BF[19], w2);
#pragma unroll
            for (int r = 0; r < 4; ++r) {
                *(uint32_t*)(wr + OFF_Z + n * 4 + r * ROWB)       = splitpk(fmaxf(w0[r] + zb3, 0.f));
                *(uint32_t*)(wr + OFF_Z + 64 + n * 4 + r * ROWB)  = splitpk(fmaxf(w1[r] + zb3, 0.f));
                *(uint32_t*)(wr + OFF_Z + 128 + n * 4 + r * ROWB) = splitpk(fmaxf(w2[r] + zb3, 0.f));
            }
            uint4 z0 = *(const uint4*)(rr + OFF_Z + q * 16);
            uint4 z1 = *(const uint4*)(rr + OFF_Z + 64 + q * 16);
            uint4 z2 = *(const uint4*)(rr + OFF_Z + 128 + q * 16);
            f32x4 g0 = mfma16(z0, BF[20], zero); g0 = mfma16(z1, BF[21], g0); g0 = mfma16(z2, BF[22], g0);
            f32x4 g1 = mfma16(z0, BF[23], zero); g1 = mfma16(z1, BF[24], g1); g1 = mfma16(z2, BF[25], g1);
            f32x4 g2 = mfma16(z0, BF[26], zero); g2 = mfma16(z1, BF[27], g2); g2 = mfma16(z2, BF[28], g2);

            float part[4];
#pragma unroll
            for (int r = 0; r < 4; ++r) {
                float h0 = jpos ? g0[r] + cb3 : 0.f;
                float h1 = (jpos ? fmaxf(g1[r], g2[r]) : g2[r]) + cb3;
                part[r] = fmaf(h0, wm0, h1 * wm1);
            }
#pragma unroll
            for (int m = 1; m < 16; m <<= 1) {
#pragma unroll
                for (int r = 0; r < 4; ++r) part[r] += __shfl_xor(part[r], m);
            }
            if (n < 4) {
                float v = part[0];
                v = (n == 1) ? part[1] : v;
                v = (n == 2) ? part[2] : v;
                v = (n == 3) ? part[3] : v;
                out[(size_t)(bg * 16 + q * 4 + n) * GC + j] = v + bm;
            }
        }

        if (it < 33) commit();
    }
}

extern "C" void kernel_launch(void* const* d_in, const int* in_sizes, int n_in,
                              void* d_out, int out_size, void* d_ws, size_t ws_size,
                              hipStream_t stream) {
    const float* x   = (const float*)d_in[0];
    const float* e   = (const float*)d_in[1];
    const float* w1a = (const float*)d_in[4];
    const float* b1a = (const float*)d_in[5];
    const float* w1b = (const float*)d_in[6];
    const float* b1b = (const float*)d_in[7];
    const float* w2a = (const float*)d_in[8];
    const float* b2a = (const float*)d_in[9];
    const float* w2b = (const float*)d_in[10];
    const float* b2b = (const float*)d_in[11];
    const float* w3a = (const float*)d_in[12];
    const float* b3a = (const float*)d_in[13];
    const float* w3b = (const float*)d_in[14];
    const float* b3b = (const float*)d_in[15];
    const float* wmu = (const float*)d_in[16];
    const float* bmu = (const float*)d_in[17];
    float* out = (float*)d_out;
    uint4* tab = (uint4*)d_ws;   // 29*64*16 = 29696 B

    hipLaunchKernelGGL(build_frags, dim3(8), dim3(256), 0, stream,
                       w1a, w1b, w2a, w2b, w3a, w3b, tab);
    hipLaunchKernelGGL(gnn_mfma, dim3(1024), dim3(256), 0, stream,
                       x, e, b1a, b1b, b2a, b2b, b3a, b3b, wmu, bmu, tab, out);
}